// Round 4
// baseline (67.513 us; speedup 1.0000x reference)
//
#include <hip/hip_runtime.h>

#define RADIUS2 0.01f
#define NS 32
#define B_ 4
#define M_ 2048
#define N_ 8192
#define C_ 64
#define OUTW 67               // 3 + C
#define PERQ (NS * OUTW)      // 2144
#define NW 8                  // waves per block == queries per block
#define NT (NW * 64)          // 512 threads
#define SLICE (N_ / NW)       // 1024 points per wave
#define NCH (SLICE / 64)      // 16 chunks per slice
#define HPTS (4 * SLICE)      // 4096 points per staging round

__global__ __launch_bounds__(NT) void ballquery_group_kernel(
    const float* __restrict__ new_xyz,   // [B, M, 3]
    const float* __restrict__ pointset,  // [B, N, 3]
    const float* __restrict__ feature,   // [B, N, C]
    float* __restrict__ out)             // [B, M, NS, 67]
{
    const int tid   = threadIdx.x;
    const int w     = tid >> 6;          // wave id = slice id; also query id in merge/phase2
    const int lane  = tid & 63;
    const int qbase = blockIdx.x * NW;
    const int b     = qbase >> 11;       // M=2048; NW | M so whole block is one batch

    __shared__ float4 spts[HPTS];        // 64 KB staging, reused for 2 rounds
    __shared__ int    lists[NW][NW][NS]; // [slice][query][slot] candidate indices
    __shared__ int    cnts[NW][NW];      // [slice][query] clamped counts
    __shared__ int    sfinal[NW][NS];    // merged per-query indices
    __shared__ float  sq[NW * 3];        // block's query coords

    const float* __restrict__ ps = pointset + (size_t)b * N_ * 3;

    if (tid < NW * 3) sq[tid] = new_xyz[qbase * 3 + tid];

    // ---- load this wave's 1024-point slice into registers (2 staging rounds) ----
    float px[NCH], py[NCH], pz[NCH];
    for (int r = 0; r < 2; ++r) {
        __syncthreads();                 // round-0 consumers done before overwrite
        {
            const float* __restrict__ tp = ps + r * HPTS * 3;
            float* __restrict__ sp = (float*)spts;
            for (int d = tid; d < HPTS * 3; d += NT) {   // coalesced dword loads
                const int p = d / 3;
                sp[p * 4 + (d - p * 3)] = tp[d];         // float4-padded in LDS
            }
        }
        __syncthreads();
        if ((w >> 2) == r) {             // waves 0-3 take round 0, 4-7 round 1
            const int ls = w & 3;
#pragma unroll
            for (int c = 0; c < NCH; ++c) {              // static indices: stays in VGPRs
                const float4 v = spts[ls * SLICE + c * 64 + lane];
                px[c] = v.x; py[c] = v.y; pz[c] = v.z;
            }
        }
    }
    __syncthreads();

    // ---- phase 1: wave w tests its slice against all NW queries ----
    for (int j = 0; j < NW; ++j) {
        const float qx = sq[j * 3 + 0];
        const float qy = sq[j * 3 + 1];
        const float qz = sq[j * 3 + 2];
        int cnt = 0;                     // wave-uniform
#pragma unroll
        for (int c = 0; c < NCH; ++c) {
            const float dx = qx - px[c];
            const float dy = qy - py[c];
            const float dz = qz - pz[c];
            // exact non-fma sum of squares (matches reference tie-breaking)
            const float d2 = __fadd_rn(__fadd_rn(__fmul_rn(dx, dx), __fmul_rn(dy, dy)),
                                       __fmul_rn(dz, dz));
            const bool in = d2 < RADIUS2;
            const unsigned long long mk = __ballot(in);
            if (mk) {
                if (in) {
                    const unsigned pre = __builtin_amdgcn_mbcnt_hi(
                        (unsigned)(mk >> 32),
                        __builtin_amdgcn_mbcnt_lo((unsigned)mk, 0u));
                    const int slot = cnt + (int)pre;
                    if (slot < NS) lists[w][j][slot] = w * SLICE + c * 64 + lane;
                }
                cnt += (int)__popcll(mk);
            }
        }
        if (lane == 0) cnts[w][j] = cnt < NS ? cnt : NS;
    }
    __syncthreads();

    // ---- merge: wave w concatenates the 8 slice lists of query w (index order) ----
    {
        int myidx = 0;                   // default 0 covers total==0 case
        int run = 0;
#pragma unroll
        for (int s = 0; s < NW; ++s) {
            const int c = cnts[s][w];    // broadcast read
            if (lane >= run && lane < run + c && lane < NS)
                myidx = lists[s][w][lane - run];
            run += c;
        }
        const int total = run < NS ? run : NS;
        const int first = __shfl(myidx, 0);              // global first index (or 0)
        if (lane < NS) sfinal[w][lane] = (lane < total) ? myidx : first;
    }
    __syncthreads();

    // ---- phase 2: wave w gathers + writes query w's output ----
    const float* __restrict__ fb = feature + (size_t)b * N_ * C_;
    float* __restrict__ outq = out + (size_t)(qbase + w) * PERQ;

    int s = 0;          // sample slot 0..31 (per-lane)
    int c = lane;       // channel 0..66 (per-lane)
    for (int o = lane; o < PERQ; o += 64) {
        const int i = sfinal[w][s];
        float v;
        if (c < 3) {
            v = ps[i * 3 + c] - sq[w * 3 + c];           // local_xyz = p - q
        } else {
            v = fb[(size_t)i * C_ + (c - 3)];
        }
        outq[o] = v;
        c += 64;
        if (c >= OUTW) { c -= OUTW; s += 1; }
    }
}

extern "C" void kernel_launch(void* const* d_in, const int* in_sizes, int n_in,
                              void* d_out, int out_size, void* d_ws, size_t ws_size,
                              hipStream_t stream) {
    const float* new_xyz  = (const float*)d_in[0];
    const float* pointset = (const float*)d_in[1];
    const float* feature  = (const float*)d_in[2];
    float* out = (float*)d_out;

    const int nq = B_ * M_;               // 8192 queries
    const int blocks = nq / NW;           // 1024 blocks of 8 waves
    ballquery_group_kernel<<<blocks, NT, 0, stream>>>(new_xyz, pointset, feature, out);
}

// Round 5
// 54.530 us; speedup vs baseline: 1.2381x; 1.2381x over previous
//
#include <hip/hip_runtime.h>

#define RADIUS2 0.01f
#define NS 32
#define B_ 4
#define M_ 2048
#define N_ 8192
#define C_ 64
#define OUTW 67               // 3 + C
#define PERQ (NS * OUTW)      // 2144
#define GD 10                 // grid cells per axis (cell width 0.1 = radius)
#define NC (GD * GD * GD)     // 1000 cells per batch
#define CAP 128               // max in-ball candidates per query (Poisson(34))

__device__ __forceinline__ int cell_of(float x, float y, float z) {
    int cx = (int)(x * 10.0f); cx = cx < 0 ? 0 : (cx > 9 ? 9 : cx);
    int cy = (int)(y * 10.0f); cy = cy < 0 ? 0 : (cy > 9 ? 9 : cy);
    int cz = (int)(z * 10.0f); cz = cz < 0 ? 0 : (cz > 9 ? 9 : cz);
    return (cz * GD + cy) * GD + cx;
}

// ---- grid build: one block per batch ----
__global__ __launch_bounds__(1024) void build_grid(
    const float* __restrict__ pointset,  // [B,N,3]
    int* __restrict__ cellstart,         // [B][NC+1]
    int* __restrict__ cellpts)           // [B][N]
{
    const int b   = blockIdx.x;
    const int tid = threadIdx.x;
    const float* __restrict__ ps = pointset + (size_t)b * N_ * 3;
    int* __restrict__ cs = cellstart + b * (NC + 1);
    int* __restrict__ cp = cellpts + b * N_;

    __shared__ int scnt[NC];
    __shared__ int sstart[NC];
    __shared__ int sfill[NC];

    for (int c = tid; c < NC; c += 1024) { scnt[c] = 0; sfill[c] = 0; }
    __syncthreads();

    for (int i = tid; i < N_; i += 1024)
        atomicAdd(&scnt[cell_of(ps[i*3], ps[i*3+1], ps[i*3+2])], 1);
    __syncthreads();

    // inclusive scan over NC cells (Hillis-Steele)
    for (int off = 1; off < NC; off <<= 1) {
        int v = 0;
        if (tid < NC && tid >= off) v = scnt[tid - off];
        __syncthreads();
        if (tid < NC) scnt[tid] += v;
        __syncthreads();
    }
    if (tid < NC) sstart[tid] = (tid == 0) ? 0 : scnt[tid - 1];
    __syncthreads();
    if (tid < NC) cs[tid] = sstart[tid];
    if (tid == 0) cs[NC] = N_;

    for (int i = tid; i < N_; i += 1024) {
        const int c = cell_of(ps[i*3], ps[i*3+1], ps[i*3+2]);
        cp[sstart[c] + atomicAdd(&sfill[c], 1)] = i;
    }
}

// ---- query + group: one wave per query ----
__global__ __launch_bounds__(256) void query_group(
    const float* __restrict__ new_xyz,   // [B,M,3]
    const float* __restrict__ pointset,  // [B,N,3]
    const float* __restrict__ feature,   // [B,N,C]
    const int* __restrict__ cellstart,   // [B][NC+1]
    const int* __restrict__ cellpts,     // [B][N]
    float* __restrict__ out)             // [B,M,NS,67]
{
    const int w    = threadIdx.x >> 6;
    const int lane = threadIdx.x & 63;
    const int q    = blockIdx.x * 4 + w;
    const int b    = q >> 11;            // q / M

    __shared__ int cand[4][CAP];
    __shared__ int sfinal[4][NS];

    const float* __restrict__ ps = pointset + (size_t)b * N_ * 3;
    const int* __restrict__ cs = cellstart + b * (NC + 1);
    const int* __restrict__ cp = cellpts + b * N_;

    const float qx = new_xyz[q*3+0];
    const float qy = new_xyz[q*3+1];
    const float qz = new_xyz[q*3+2];

    int cx = (int)(qx * 10.0f); cx = cx < 0 ? 0 : (cx > 9 ? 9 : cx);
    int cy = (int)(qy * 10.0f); cy = cy < 0 ? 0 : (cy > 9 ? 9 : cy);
    int cz = (int)(qz * 10.0f); cz = cz < 0 ? 0 : (cz > 9 ? 9 : cz);
    const int x0 = cx > 0 ? cx - 1 : 0, x1 = cx < 9 ? cx + 1 : 9;
    const int y0 = cy > 0 ? cy - 1 : 0, y1 = cy < 9 ? cy + 1 : 9;
    const int z0 = cz > 0 ? cz - 1 : 0, z1 = cz < 9 ? cz + 1 : 9;

    // collect in-ball candidates from up to 9 contiguous x-row ranges
    int ncand = 0;
    for (int zz = z0; zz <= z1; ++zz) {
        for (int yy = y0; yy <= y1; ++yy) {
            const int base = (zz * GD + yy) * GD;
            const int s = cs[base + x0];
            const int e = cs[base + x1 + 1];
            for (int j0 = s; j0 < e; j0 += 64) {        // wave-uniform trip count
                const int j  = j0 + lane;
                const int jj = j < e ? j : e - 1;
                const int idx = cp[jj];
                const float dx = qx - ps[idx*3+0];
                const float dy = qy - ps[idx*3+1];
                const float dz = qz - ps[idx*3+2];
                // exact non-fma sum of squares (matches reference tie-breaking)
                const float d2 = __fadd_rn(__fadd_rn(__fmul_rn(dx,dx), __fmul_rn(dy,dy)),
                                           __fmul_rn(dz,dz));
                const bool in = (j < e) && (d2 < RADIUS2);
                const unsigned long long mk = __ballot(in);
                if (in) {
                    const unsigned pre = __builtin_amdgcn_mbcnt_hi(
                        (unsigned)(mk >> 32),
                        __builtin_amdgcn_mbcnt_lo((unsigned)mk, 0u));
                    const int slot = ncand + (int)pre;
                    if (slot < CAP) cand[w][slot] = idx;
                }
                ncand += (int)__popcll(mk);
            }
        }
    }
    if (ncand > CAP) ncand = CAP;
    __syncthreads();

    // rank candidates by original index (distinct -> unique ranks)
    const int v0 = (lane       < ncand) ? cand[w][lane]      : 0x7fffffff;
    const int v1 = (lane + 64  < ncand) ? cand[w][lane + 64] : 0x7fffffff;
    int r0 = 0, r1 = 0;
    for (int j = 0; j < ncand; ++j) {
        const int cj = cand[w][j];       // broadcast read
        r0 += (cj < v0);
        r1 += (cj < v1);
    }
    const int cnt = ncand < NS ? ncand : NS;
    if (v0 != 0x7fffffff && r0 < NS) sfinal[w][r0] = v0;
    if (v1 != 0x7fffffff && r1 < NS) sfinal[w][r1] = v1;
    __syncthreads();

    // fill slots >= cnt with first (lowest) index; 0 if none — CUDA semantics
    const int first = (cnt > 0) ? sfinal[w][0] : 0;
    if (lane < NS && lane >= cnt) sfinal[w][lane] = first;
    __syncthreads();

    // gather + concat
    const float* __restrict__ fb = feature + (size_t)b * N_ * C_;
    float* __restrict__ outq = out + (size_t)q * PERQ;

    int s = 0, c = lane;
    for (int o = lane; o < PERQ; o += 64) {
        const int i = sfinal[w][s];
        float v;
        if (c < 3) {
            v = ps[i*3+c] - new_xyz[q*3+c];            // local_xyz = p - q
        } else {
            v = fb[(size_t)i * C_ + (c - 3)];
        }
        outq[o] = v;
        c += 64;
        if (c >= OUTW) { c -= OUTW; s += 1; }
    }
}

// ---- fallback (proven R3 kernel) if ws is too small ----
#define NWF 8
#define TILEF 1024
#define NTILEF (N_ / TILEF)

__global__ __launch_bounds__(NWF * 64) void ballquery_fallback(
    const float* __restrict__ new_xyz, const float* __restrict__ pointset,
    const float* __restrict__ feature, float* __restrict__ out)
{
    const int tid  = threadIdx.x;
    const int w    = tid >> 6;
    const int lane = tid & 63;
    const int q    = blockIdx.x * NWF + w;
    const int b    = q >> 11;

    __shared__ float4 spts[TILEF];
    __shared__ int    sidx[NWF][NS];
    __shared__ int    s_done;

    const float qx = new_xyz[q*3+0], qy = new_xyz[q*3+1], qz = new_xyz[q*3+2];
    const float* __restrict__ ps = pointset + (size_t)b * N_ * 3;

    if (tid == 0) s_done = 0;
    int cnt = 0; bool counted = false;

    for (int t = 0; t < NTILEF; ++t) {
        __syncthreads();
        if (s_done == NWF) break;
        {
            const float* __restrict__ tp = ps + t * TILEF * 3;
            float* __restrict__ sp = (float*)spts;
            for (int d = tid; d < TILEF * 3; d += NWF * 64) {
                const int p = d / 3;
                sp[p * 4 + (d - p * 3)] = tp[d];
            }
        }
        __syncthreads();
        if (cnt < NS) {
#pragma unroll 4
            for (int it = 0; it < TILEF / 64; ++it) {
                const float4 p = spts[it * 64 + lane];
                const float dx = qx - p.x, dy = qy - p.y, dz = qz - p.z;
                const float d2 = __fadd_rn(__fadd_rn(__fmul_rn(dx,dx), __fmul_rn(dy,dy)),
                                           __fmul_rn(dz,dz));
                const bool in = d2 < RADIUS2;
                const unsigned long long mk = __ballot(in);
                const unsigned pre = __builtin_amdgcn_mbcnt_hi(
                    (unsigned)(mk >> 32), __builtin_amdgcn_mbcnt_lo((unsigned)mk, 0u));
                if (in) {
                    const int slot = cnt + (int)pre;
                    if (slot < NS) sidx[w][slot] = t * TILEF + it * 64 + lane;
                }
                cnt += (int)__popcll(mk);
            }
        }
        if (!counted && cnt >= NS) { counted = true; if (lane == 0) atomicAdd(&s_done, 1); }
    }
    if (cnt > NS) cnt = NS;
    const int first = (cnt > 0) ? sidx[w][0] : 0;
    if (lane < NS && lane >= cnt) sidx[w][lane] = first;

    const float* __restrict__ fb = feature + (size_t)b * N_ * C_;
    float* __restrict__ outq = out + (size_t)q * PERQ;
    int s = 0, c = lane;
    for (int o = lane; o < PERQ; o += 64) {
        const int i = sidx[w][s];
        float v;
        if (c < 3) v = ps[i*3+c] - new_xyz[q*3+c];
        else       v = fb[(size_t)i * C_ + (c - 3)];
        outq[o] = v;
        c += 64;
        if (c >= OUTW) { c -= OUTW; s += 1; }
    }
}

extern "C" void kernel_launch(void* const* d_in, const int* in_sizes, int n_in,
                              void* d_out, int out_size, void* d_ws, size_t ws_size,
                              hipStream_t stream) {
    const float* new_xyz  = (const float*)d_in[0];
    const float* pointset = (const float*)d_in[1];
    const float* feature  = (const float*)d_in[2];
    float* out = (float*)d_out;

    const size_t needed = (size_t)B_ * ((NC + 1) + N_) * sizeof(int);
    if (ws_size >= needed) {
        int* cellstart = (int*)d_ws;                       // [B][NC+1]
        int* cellpts   = cellstart + B_ * (NC + 1);        // [B][N]
        build_grid<<<B_, 1024, 0, stream>>>(pointset, cellstart, cellpts);
        query_group<<<(B_ * M_) / 4, 256, 0, stream>>>(
            new_xyz, pointset, feature, cellstart, cellpts, out);
    } else {
        ballquery_fallback<<<(B_ * M_) / NWF, NWF * 64, 0, stream>>>(
            new_xyz, pointset, feature, out);
    }
}

// Round 7
// 48.380 us; speedup vs baseline: 1.3955x; 1.1271x over previous
//
#include <hip/hip_runtime.h>

#define RADIUS2 0.01f
#define NS 32
#define B_ 4
#define M_ 2048
#define N_ 8192
#define C_ 64
#define OUTW 67               // 3 + C
#define PERQ (NS * OUTW)      // 2144 floats; *4 = 8576 B (16B aligned)
#define PERQ4 (PERQ / 4)      // 536 float4 per query
#define GD 10                 // cells per axis (cell width = radius)
#define NC (GD * GD * GD)     // 1000
#define CAP 128               // max candidates kept (Poisson(34); P(>128)~1e-30)

typedef float f32x4 __attribute__((ext_vector_type(4)));  // native vec for nt-store

__device__ __forceinline__ int clamp9(int v) { return v < 0 ? 0 : (v > 9 ? 9 : v); }

// ---- grid build: one block per batch; also emits points sorted by cell ----
__global__ __launch_bounds__(1024) void build_grid(
    const float* __restrict__ pointset,  // [B,N,3]
    int* __restrict__ cellstart,         // [B][NC+1]
    float4* __restrict__ sorted4)        // [B][N]: x,y,z,orig-idx bits
{
    const int b   = blockIdx.x;
    const int tid = threadIdx.x;
    const float* __restrict__ ps = pointset + (size_t)b * N_ * 3;
    int* __restrict__ cs = cellstart + b * (NC + 1);
    float4* __restrict__ sp = sorted4 + (size_t)b * N_;

    __shared__ int scnt[NC], sstart[NC], sfill[NC];

    for (int c = tid; c < NC; c += 1024) { scnt[c] = 0; sfill[c] = 0; }
    __syncthreads();

    for (int i = tid; i < N_; i += 1024) {
        const int cx = clamp9((int)(ps[i*3+0] * 10.f));
        const int cy = clamp9((int)(ps[i*3+1] * 10.f));
        const int cz = clamp9((int)(ps[i*3+2] * 10.f));
        atomicAdd(&scnt[(cz * GD + cy) * GD + cx], 1);
    }
    __syncthreads();

    for (int off = 1; off < NC; off <<= 1) {       // inclusive scan
        int v = 0;
        if (tid < NC && tid >= off) v = scnt[tid - off];
        __syncthreads();
        if (tid < NC) scnt[tid] += v;
        __syncthreads();
    }
    if (tid < NC) sstart[tid] = tid ? scnt[tid - 1] : 0;
    __syncthreads();
    if (tid < NC) cs[tid] = sstart[tid];
    if (tid == 0) cs[NC] = N_;

    for (int i = tid; i < N_; i += 1024) {
        const float x = ps[i*3+0], y = ps[i*3+1], z = ps[i*3+2];
        const int c = (clamp9((int)(z * 10.f)) * GD + clamp9((int)(y * 10.f))) * GD
                      + clamp9((int)(x * 10.f));
        const int pos = sstart[c] + atomicAdd(&sfill[c], 1);
        sp[pos] = make_float4(x, y, z, __int_as_float(i));
    }
}

// ---- query + group: one wave per query; no cross-wave LDS -> no barriers ----
__global__ __launch_bounds__(256) void query_group(
    const float* __restrict__ new_xyz,   // [B,M,3]
    const float* __restrict__ pointset,  // [B,N,3]
    const float* __restrict__ feature,   // [B,N,C]
    const int* __restrict__ cellstart,   // [B][NC+1]
    const float4* __restrict__ sorted4,  // [B][N]
    float* __restrict__ out)             // [B,M,NS,67]
{
    const int w    = threadIdx.x >> 6;
    const int lane = threadIdx.x & 63;
    const int q    = blockIdx.x * 4 + w;
    const int b    = q >> 11;            // q / M

    __shared__ int cand[4][CAP];         // per-wave only
    __shared__ int sfinal[4][NS];        // per-wave only

    const float* __restrict__ ps = pointset + (size_t)b * N_ * 3;
    const int* __restrict__ cs = cellstart + b * (NC + 1);
    const float4* __restrict__ sp4 = sorted4 + (size_t)b * N_;

    const float qx = new_xyz[q*3+0];
    const float qy = new_xyz[q*3+1];
    const float qz = new_xyz[q*3+2];

    const int cx = clamp9((int)(qx * 10.f));
    const int cy = clamp9((int)(qy * 10.f));
    const int cz = clamp9((int)(qz * 10.f));
    const int x0 = cx > 0 ? cx - 1 : 0, x1 = cx < 9 ? cx + 1 : 9;
    const int y0 = cy > 0 ? cy - 1 : 0, y1 = cy < 9 ? cy + 1 : 9;
    const int z0 = cz > 0 ? cz - 1 : 0, z1 = cz < 9 ? cz + 1 : 9;

    // collect in-ball candidates from <=9 contiguous, coalesced x-row ranges
    int ncand = 0;
    for (int zz = z0; zz <= z1; ++zz) {
        for (int yy = y0; yy <= y1; ++yy) {
            const int base = (zz * GD + yy) * GD;
            const int s = cs[base + x0];
            const int e = cs[base + x1 + 1];
            for (int j0 = s; j0 < e; j0 += 64) {         // wave-uniform trips
                const int j = j0 + lane;
                const float4 v = sp4[j < e ? j : e - 1]; // coalesced dwordx4
                const float dx = qx - v.x;
                const float dy = qy - v.y;
                const float dz = qz - v.z;
                // exact non-fma sum of squares (matches reference ties)
                const float d2 = __fadd_rn(__fadd_rn(__fmul_rn(dx,dx), __fmul_rn(dy,dy)),
                                           __fmul_rn(dz,dz));
                const bool in = (j < e) && (d2 < RADIUS2);
                const unsigned long long mk = __ballot(in);
                if (in) {
                    const unsigned pre = __builtin_amdgcn_mbcnt_hi(
                        (unsigned)(mk >> 32),
                        __builtin_amdgcn_mbcnt_lo((unsigned)mk, 0u));
                    const int slot = ncand + (int)pre;
                    if (slot < CAP) cand[w][slot] = __float_as_int(v.w);
                }
                ncand += (int)__popcll(mk);
            }
        }
    }
    if (ncand > CAP) ncand = CAP;

    // rank candidates by original index -> first-32-in-index-order semantics
    const int v0 = (lane      < ncand) ? cand[w][lane]      : 0x7fffffff;
    const int v1 = (lane + 64 < ncand) ? cand[w][lane + 64] : 0x7fffffff;
    int r0 = 0, r1 = 0;
    for (int j = 0; j < ncand; ++j) {
        const int cj = cand[w][j];       // broadcast read
        r0 += (cj < v0);
        r1 += (cj < v1);
    }
    const int cnt = ncand < NS ? ncand : NS;
    if (v0 != 0x7fffffff && r0 < NS) sfinal[w][r0] = v0;
    if (v1 != 0x7fffffff && r1 < NS) sfinal[w][r1] = v1;

    // fill slots >= cnt with first (lowest) index; 0 if none — CUDA semantics
    const int first = (cnt > 0) ? sfinal[w][0] : 0;
    if (lane < NS && lane >= cnt) sfinal[w][lane] = first;

    // ---- gather + concat, float4 nontemporal stores ----
    const float* __restrict__ fb = feature + (size_t)b * N_ * C_;
    f32x4* __restrict__ outq4 = (f32x4*)(out + (size_t)q * PERQ);

    for (int o4 = lane; o4 < PERQ4; o4 += 64) {
        const int o = o4 * 4;
        int s = (o * 1957) >> 17;        // exact /67 for o in [0,2144)
        int c = o - s * 67;
        f32x4 v;
#pragma unroll
        for (int e = 0; e < 4; ++e) {
            const int i = sfinal[w][s];
            float val;
            if (c < 3) val = ps[i*3 + c] - new_xyz[q*3 + c];   // local_xyz = p - q
            else       val = fb[(size_t)i * C_ + (c - 3)];
            v[e] = val;
            if (++c == OUTW) { c = 0; ++s; }
        }
        __builtin_nontemporal_store(v, outq4 + o4);
    }
}

// ---- fallback (proven R3 kernel) if ws too small ----
#define NWF 8
#define TILEF 1024
#define NTILEF (N_ / TILEF)

__global__ __launch_bounds__(NWF * 64) void ballquery_fallback(
    const float* __restrict__ new_xyz, const float* __restrict__ pointset,
    const float* __restrict__ feature, float* __restrict__ out)
{
    const int tid  = threadIdx.x;
    const int w    = tid >> 6;
    const int lane = tid & 63;
    const int q    = blockIdx.x * NWF + w;
    const int b    = q >> 11;

    __shared__ float4 spts[TILEF];
    __shared__ int    sidx[NWF][NS];
    __shared__ int    s_done;

    const float qx = new_xyz[q*3+0], qy = new_xyz[q*3+1], qz = new_xyz[q*3+2];
    const float* __restrict__ ps = pointset + (size_t)b * N_ * 3;

    if (tid == 0) s_done = 0;
    int cnt = 0; bool counted = false;

    for (int t = 0; t < NTILEF; ++t) {
        __syncthreads();
        if (s_done == NWF) break;
        {
            const float* __restrict__ tp = ps + t * TILEF * 3;
            float* __restrict__ sp = (float*)spts;
            for (int d = tid; d < TILEF * 3; d += NWF * 64) {
                const int p = d / 3;
                sp[p * 4 + (d - p * 3)] = tp[d];
            }
        }
        __syncthreads();
        if (cnt < NS) {
#pragma unroll 4
            for (int it = 0; it < TILEF / 64; ++it) {
                const float4 p = spts[it * 64 + lane];
                const float dx = qx - p.x, dy = qy - p.y, dz = qz - p.z;
                const float d2 = __fadd_rn(__fadd_rn(__fmul_rn(dx,dx), __fmul_rn(dy,dy)),
                                           __fmul_rn(dz,dz));
                const bool in = d2 < RADIUS2;
                const unsigned long long mk = __ballot(in);
                const unsigned pre = __builtin_amdgcn_mbcnt_hi(
                    (unsigned)(mk >> 32), __builtin_amdgcn_mbcnt_lo((unsigned)mk, 0u));
                if (in) {
                    const int slot = cnt + (int)pre;
                    if (slot < NS) sidx[w][slot] = t * TILEF + it * 64 + lane;
                }
                cnt += (int)__popcll(mk);
            }
        }
        if (!counted && cnt >= NS) { counted = true; if (lane == 0) atomicAdd(&s_done, 1); }
    }
    if (cnt > NS) cnt = NS;
    const int first = (cnt > 0) ? sidx[w][0] : 0;
    if (lane < NS && lane >= cnt) sidx[w][lane] = first;

    const float* __restrict__ fb = feature + (size_t)b * N_ * C_;
    float* __restrict__ outq = out + (size_t)q * PERQ;
    int s = 0, c = lane;
    for (int o = lane; o < PERQ; o += 64) {
        const int i = sidx[w][s];
        float v;
        if (c < 3) v = ps[i*3+c] - new_xyz[q*3+c];
        else       v = fb[(size_t)i * C_ + (c - 3)];
        outq[o] = v;
        c += 64;
        if (c >= OUTW) { c -= OUTW; s += 1; }
    }
}

extern "C" void kernel_launch(void* const* d_in, const int* in_sizes, int n_in,
                              void* d_out, int out_size, void* d_ws, size_t ws_size,
                              hipStream_t stream) {
    const float* new_xyz  = (const float*)d_in[0];
    const float* pointset = (const float*)d_in[1];
    const float* feature  = (const float*)d_in[2];
    float* out = (float*)d_out;

    const size_t cs_bytes = (size_t)B_ * (NC + 1) * sizeof(int);   // 16016 (16B aligned)
    const size_t needed   = cs_bytes + (size_t)B_ * N_ * sizeof(float4);
    if (ws_size >= needed) {
        int*    cellstart = (int*)d_ws;
        float4* sorted4   = (float4*)((char*)d_ws + cs_bytes);
        build_grid<<<B_, 1024, 0, stream>>>(pointset, cellstart, sorted4);
        query_group<<<(B_ * M_) / 4, 256, 0, stream>>>(
            new_xyz, pointset, feature, cellstart, sorted4, out);
    } else {
        ballquery_fallback<<<(B_ * M_) / NWF, NWF * 64, 0, stream>>>(
            new_xyz, pointset, feature, out);
    }
}